// Round 2
// baseline (171.978 us; speedup 1.0000x reference)
//
#include <hip/hip_runtime.h>

// Problem constants (B=8, T=4096, D=1024, C=64, P=512)
// Outputs are FLOAT32, concatenated: pattern_emb, assignments, logits, hard_indices, Q
#define O_PE 0
#define O_AS 33554432
#define O_LG 50331648
#define O_HI 67108864
#define O_Q  67141632

// ---------------------------------------------------------------------------
// K0: precompute  (grid = 512 blocks, one per pattern)
//  - inv temperature
//  - K_norm transposed:  knT[c][p]  (fp32, [64][512])
//  - PE table: LN(patterns @ w2 + b2) as fp32 [512][1024]
// ---------------------------------------------------------------------------
__global__ void k0_pre(const float* __restrict__ patterns, const float* __restrict__ w2,
                       const float* __restrict__ b2, const float* __restrict__ ln2g,
                       const float* __restrict__ ln2b, const int* __restrict__ epoch,
                       const int* __restrict__ total_epochs,
                       float* __restrict__ invt, float* __restrict__ knT,
                       float* __restrict__ peb) {
  const int b = blockIdx.x, t = threadIdx.x;
  __shared__ float pat[64];
  __shared__ float red[8];

  if (b == 0 && t == 0) {
    float ep = (float)epoch[0], te = (float)total_epochs[0];
    float warm = te * 0.1f;
    float temp;
    if (ep < warm) temp = 2.0f;
    else {
      float prog = (ep - warm) / (te - warm);
      temp = fmaxf(0.7f, 2.0f - 1.3f * prog);
    }
    invt[0] = 1.0f / temp;
  }

  if (t < 64) pat[t] = patterns[b * 64 + t];
  __syncthreads();

  // l2-normalized pattern row -> knT (transposed)
  if (t < 64) {
    float v = pat[t];
    float s = v * v;
    #pragma unroll
    for (int m = 1; m < 64; m <<= 1) s += __shfl_xor(s, m);
    float scale = 1.0f / fmaxf(sqrtf(s), 1e-12f);
    knT[(size_t)t * 512 + b] = v * scale;
  }

  // PE row: y[d] = pat . w2[:,d] + b2[d] ; then LayerNorm over d
  const int d0 = t * 4;
  float4 acc = *(const float4*)&b2[d0];
  #pragma unroll 8
  for (int k = 0; k < 64; ++k) {
    float pk = pat[k];
    float4 w = *(const float4*)&w2[(size_t)k * 1024 + d0];
    acc.x = fmaf(pk, w.x, acc.x);
    acc.y = fmaf(pk, w.y, acc.y);
    acc.z = fmaf(pk, w.z, acc.z);
    acc.w = fmaf(pk, w.w, acc.w);
  }
  float s1 = acc.x + acc.y + acc.z + acc.w;
  float s2 = acc.x*acc.x + acc.y*acc.y + acc.z*acc.z + acc.w*acc.w;
  #pragma unroll
  for (int m = 1; m < 64; m <<= 1) { s1 += __shfl_xor(s1, m); s2 += __shfl_xor(s2, m); }
  const int wid = t >> 6;
  if ((t & 63) == 0) { red[wid] = s1; red[wid + 4] = s2; }
  __syncthreads();
  s1 = red[0] + red[1] + red[2] + red[3];
  s2 = red[4] + red[5] + red[6] + red[7];
  float mu = s1 * (1.0f / 1024.0f);
  float var = s2 * (1.0f / 1024.0f) - mu * mu;
  float rstd = rsqrtf(var + 1e-5f);
  float4 g  = *(const float4*)&ln2g[d0];
  float4 bb = *(const float4*)&ln2b[d0];
  float4 o;
  o.x = (acc.x - mu) * rstd * g.x + bb.x;
  o.y = (acc.y - mu) * rstd * g.y + bb.y;
  o.z = (acc.z - mu) * rstd * g.z + bb.z;
  o.w = (acc.w - mu) * rstd * g.w + bb.w;
  *(float4*)&peb[(size_t)b * 1024 + d0] = o;
}

// ---------------------------------------------------------------------------
// K1: fused GEMM1 + LN + l2norm + logits + argmax + assignments
// grid = 512 blocks x 256 threads; 64 rows per block.
// Thread owns a 4x4 register tile: rows r0..r0+3, cols/patterns c0..c0+3.
// ---------------------------------------------------------------------------
#define FMA16(AV, BV, A)                              \
  A[0][0] = fmaf(AV.x, BV.x, A[0][0]);                \
  A[0][1] = fmaf(AV.x, BV.y, A[0][1]);                \
  A[0][2] = fmaf(AV.x, BV.z, A[0][2]);                \
  A[0][3] = fmaf(AV.x, BV.w, A[0][3]);                \
  A[1][0] = fmaf(AV.y, BV.x, A[1][0]);                \
  A[1][1] = fmaf(AV.y, BV.y, A[1][1]);                \
  A[1][2] = fmaf(AV.y, BV.z, A[1][2]);                \
  A[1][3] = fmaf(AV.y, BV.w, A[1][3]);                \
  A[2][0] = fmaf(AV.z, BV.x, A[2][0]);                \
  A[2][1] = fmaf(AV.z, BV.y, A[2][1]);                \
  A[2][2] = fmaf(AV.z, BV.z, A[2][2]);                \
  A[2][3] = fmaf(AV.z, BV.w, A[2][3]);                \
  A[3][0] = fmaf(AV.w, BV.x, A[3][0]);                \
  A[3][1] = fmaf(AV.w, BV.y, A[3][1]);                \
  A[3][2] = fmaf(AV.w, BV.z, A[3][2]);                \
  A[3][3] = fmaf(AV.w, BV.w, A[3][3]);

__global__ __launch_bounds__(256, 2) void k1_main(
    const float* __restrict__ x, const float* __restrict__ w1,
    const float* __restrict__ b1, const float* __restrict__ ln1g,
    const float* __restrict__ ln1b, const float* __restrict__ knT,
    const float* __restrict__ invtp,
    float* __restrict__ outQ, float* __restrict__ outLg,
    float* __restrict__ outAs, float* __restrict__ outHi,
    int* __restrict__ idxw) {
  __shared__ float xsT[64][68];   // [k][row]  (x tile, transposed)
  __shared__ float wks[64][68];   // [k][col]  w1 tile in phase 1, K_norm^T tile in phase 2
  __shared__ float qnT[64][68];   // [c][row]  Q_norm transposed
  __shared__ int   sidx[64];

  const int tid = threadIdx.x;
  const int rowbase = blockIdx.x * 64;
  const int r0 = (tid >> 4) * 4;
  const int c0 = (tid & 15) * 4;

  // ---------------- phase 1: Q = x @ w1 ----------------
  float acc[4][4] = {{0.f, 0.f, 0.f, 0.f}, {0.f, 0.f, 0.f, 0.f},
                     {0.f, 0.f, 0.f, 0.f}, {0.f, 0.f, 0.f, 0.f}};
  for (int kt = 0; kt < 16; ++kt) {
    const int dbase = kt * 64;
    #pragma unroll
    for (int pass = 0; pass < 4; ++pass) {
      const int rp = (tid >> 4) + pass * 16;   // doubles as k index for w1 tile
      const int dd = (tid & 15) * 4;
      float4 xv = *(const float4*)&x[(size_t)(rowbase + rp) * 1024 + dbase + dd];
      xsT[dd + 0][rp] = xv.x; xsT[dd + 1][rp] = xv.y;
      xsT[dd + 2][rp] = xv.z; xsT[dd + 3][rp] = xv.w;
      *(float4*)&wks[rp][dd] = *(const float4*)&w1[(size_t)(dbase + rp) * 64 + dd];
    }
    __syncthreads();
    #pragma unroll 8
    for (int k = 0; k < 64; ++k) {
      float4 xv = *(float4*)&xsT[k][r0];
      float4 wv = *(float4*)&wks[k][c0];
      FMA16(xv, wv, acc)
    }
    __syncthreads();
  }

  // ---------------- phase 1 epilogue: +b1, LayerNorm, l2norm ----------------
  {
    float4 b1v = *(const float4*)&b1[c0];
    float4 g1v = *(const float4*)&ln1g[c0];
    float4 e1v = *(const float4*)&ln1b[c0];
    #pragma unroll
    for (int i = 0; i < 4; ++i) {
      float h0 = acc[i][0] + b1v.x;
      float h1 = acc[i][1] + b1v.y;
      float h2 = acc[i][2] + b1v.z;
      float h3 = acc[i][3] + b1v.w;
      float s1 = h0 + h1 + h2 + h3;
      float s2 = h0*h0 + h1*h1 + h2*h2 + h3*h3;
      #pragma unroll
      for (int m = 1; m < 16; m <<= 1) { s1 += __shfl_xor(s1, m); s2 += __shfl_xor(s2, m); }
      float mu   = s1 * 0.015625f;
      float var  = s2 * 0.015625f - mu * mu;
      float rstd = rsqrtf(var + 1e-5f);
      float q0 = (h0 - mu) * rstd * g1v.x + e1v.x;
      float q1 = (h1 - mu) * rstd * g1v.y + e1v.y;
      float q2 = (h2 - mu) * rstd * g1v.z + e1v.z;
      float q3 = (h3 - mu) * rstd * g1v.w + e1v.w;
      float t2 = q0*q0 + q1*q1 + q2*q2 + q3*q3;
      #pragma unroll
      for (int m = 1; m < 16; m <<= 1) t2 += __shfl_xor(t2, m);
      float scl = 1.0f / fmaxf(sqrtf(t2), 1e-12f);
      float4 qo; qo.x = q0; qo.y = q1; qo.z = q2; qo.w = q3;
      *(float4*)&outQ[(size_t)(rowbase + r0 + i) * 64 + c0] = qo;
      qnT[c0 + 0][r0 + i] = q0 * scl;
      qnT[c0 + 1][r0 + i] = q1 * scl;
      qnT[c0 + 2][r0 + i] = q2 * scl;
      qnT[c0 + 3][r0 + i] = q3 * scl;
    }
  }

  // ---------------- phase 2: logits + argmax ----------------
  const float invt = invtp[0];
  float bmax[4]; int bidx[4];
  #pragma unroll
  for (int i = 0; i < 4; ++i) { bmax[i] = -3.0e38f; bidx[i] = 0; }

  for (int pt = 0; pt < 8; ++pt) {
    __syncthreads();
    #pragma unroll
    for (int pass = 0; pass < 4; ++pass) {
      const int cc = (tid >> 4) + pass * 16;
      const int pp = (tid & 15) * 4;
      *(float4*)&wks[cc][pp] = *(const float4*)&knT[(size_t)cc * 512 + pt * 64 + pp];
    }
    __syncthreads();
    float a2[4][4] = {{0.f, 0.f, 0.f, 0.f}, {0.f, 0.f, 0.f, 0.f},
                      {0.f, 0.f, 0.f, 0.f}, {0.f, 0.f, 0.f, 0.f}};
    #pragma unroll 8
    for (int k = 0; k < 64; ++k) {
      float4 qv = *(float4*)&qnT[k][r0];
      float4 kv = *(float4*)&wks[k][c0];
      FMA16(qv, kv, a2)
    }
    #pragma unroll
    for (int i = 0; i < 4; ++i) {
      float v0 = a2[i][0] * invt;
      float v1 = a2[i][1] * invt;
      float v2 = a2[i][2] * invt;
      float v3 = a2[i][3] * invt;
      const int pb = pt * 64 + c0;
      if (v0 > bmax[i]) { bmax[i] = v0; bidx[i] = pb; }
      if (v1 > bmax[i]) { bmax[i] = v1; bidx[i] = pb + 1; }
      if (v2 > bmax[i]) { bmax[i] = v2; bidx[i] = pb + 2; }
      if (v3 > bmax[i]) { bmax[i] = v3; bidx[i] = pb + 3; }
      float4 lo; lo.x = v0; lo.y = v1; lo.z = v2; lo.w = v3;
      *(float4*)&outLg[(size_t)(rowbase + r0 + i) * 512 + pb] = lo;
    }
  }

  // reduce argmax across the 16 lanes sharing each row group (first-index ties)
  #pragma unroll
  for (int i = 0; i < 4; ++i) {
    #pragma unroll
    for (int m = 1; m < 16; m <<= 1) {
      float ov = __shfl_xor(bmax[i], m);
      int   oi = __shfl_xor(bidx[i], m);
      if (ov > bmax[i] || (ov == bmax[i] && oi < bidx[i])) { bmax[i] = ov; bidx[i] = oi; }
    }
  }
  if ((tid & 15) == 0) {
    #pragma unroll
    for (int i = 0; i < 4; ++i) {
      sidx[r0 + i] = bidx[i];
      idxw[rowbase + r0 + i] = bidx[i];                 // exact index for gather
      outHi[rowbase + r0 + i] = (float)bidx[i];         // fp32 output
    }
  }
  __syncthreads();

  // ---------------- assignments: one-hot rows fp32, 4 floats per 16B store ----------------
  #pragma unroll
  for (int pass = 0; pass < 32; ++pass) {
    const int ch  = tid + pass * 256;    // 8192 chunks of 4 floats (128 per row)
    const int r   = ch >> 7;
    const int pcc = (ch & 127) * 4;
    const int bi  = sidx[r];
    float4 z; z.x = 0.f; z.y = 0.f; z.z = 0.f; z.w = 0.f;
    if (bi >= pcc && bi < pcc + 4) ((float*)&z)[bi - pcc] = 1.0f;
    *(float4*)&outAs[(size_t)(rowbase + r) * 512 + pcc] = z;
  }
}

// ---------------------------------------------------------------------------
// K3: pattern_emb gather — out[n,:] = PE[idx[n],:]   (fp32, 16B chunks)
// grid = 8192 blocks x 256 threads, 4 rows per block (row = 256 float4)
// ---------------------------------------------------------------------------
__global__ void k3_gather(const float4* __restrict__ peb, const int* __restrict__ idxw,
                          float4* __restrict__ outPe) {
  const int tid = threadIdx.x;
  const int rbase = blockIdx.x * 4;
  #pragma unroll
  for (int pass = 0; pass < 4; ++pass) {
    const int r = rbase + pass;
    const int idx = idxw[r];
    outPe[(size_t)r * 256 + tid] = peb[(size_t)idx * 256 + tid];
  }
}

// ---------------------------------------------------------------------------
extern "C" void kernel_launch(void* const* d_in, const int* in_sizes, int n_in,
                              void* d_out, int out_size, void* d_ws, size_t ws_size,
                              hipStream_t stream) {
  (void)in_sizes; (void)n_in; (void)out_size; (void)ws_size;
  const float* x        = (const float*)d_in[0];
  const float* w1       = (const float*)d_in[1];
  const float* b1       = (const float*)d_in[2];
  const float* ln1g     = (const float*)d_in[3];
  const float* ln1b     = (const float*)d_in[4];
  const float* patterns = (const float*)d_in[5];
  const float* w2       = (const float*)d_in[6];
  const float* b2       = (const float*)d_in[7];
  const float* ln2g     = (const float*)d_in[8];
  const float* ln2b     = (const float*)d_in[9];
  const int*   epoch    = (const int*)d_in[10];
  const int*   total    = (const int*)d_in[11];

  float* out = (float*)d_out;
  float* outPe = out + O_PE;
  float* outAs = out + O_AS;
  float* outLg = out + O_LG;
  float* outHi = out + O_HI;
  float* outQ  = out + O_Q;

  // workspace layout (bytes):
  //   [0..256)           invt (+pad)
  //   [256..131328)      knT  f32 [64][512]
  //   [131328..2228480)  PE   f32 [512][1024]
  //   [2228480..2359552) idx  int [32768]
  float* wsf  = (float*)d_ws;
  float* invt = wsf;
  float* knT  = wsf + 64;
  float* peb  = (float*)((char*)d_ws + 131328);
  int*   idxw = (int*)((char*)d_ws + 2228480);

  hipLaunchKernelGGL(k0_pre, dim3(512), dim3(256), 0, stream,
                     patterns, w2, b2, ln2g, ln2b, epoch, total, invt, knT, peb);
  hipLaunchKernelGGL(k1_main, dim3(512), dim3(256), 0, stream,
                     x, w1, b1, ln1g, ln1b, knT, invt, outQ, outLg, outAs, outHi, idxw);
  hipLaunchKernelGGL(k3_gather, dim3(8192), dim3(256), 0, stream,
                     (const float4*)peb, idxw, (float4*)outPe);
}